// Round 7
// baseline (566.742 us; speedup 1.0000x reference)
//
#include <hip/hip_runtime.h>
#include <hip/hip_bf16.h>

// ---------------------------------------------------------------------------
// GIN multi-task forward on MI355X.
// R7: barrier-free LDS-free split-bf16 MFMA GEMM. Each wave owns 16 rows x
// 128 cols; A fragments loaded straight from row-major global (8 consecutive
// k per lane) + converted to bf16 hi/lo in registers; W fragments loaded from
// the transposed bf16 Wt[n][k] (L2-resident, 64KB). No __shared__, no
// __syncthreads. R6's LDS-staged version was barrier/staging-bound (~60us);
// ideal is ~10us (51MB traffic). nt-loads in fill/hist reverted (R6: neutral
// WRITE_SIZE, slight dur regression -> nt does not prevent L2 allocation).
// ---------------------------------------------------------------------------

#define IN_DIM 128
#define NPART 8          // one partition per XCD

typedef float  f32x4  __attribute__((ext_vector_type(4)));
typedef short  bf16x8 __attribute__((ext_vector_type(8)));

__device__ __forceinline__ unsigned short bf16_rne(float v) {
    unsigned u = __float_as_uint(v);
    unsigned t = u + 0x7fffu + ((u >> 16) & 1u);
    return (unsigned short)(t >> 16);
}

// ---------------- fp32 -> bf16 convert (RNE), 8 elems/thread ---------------

__global__ __launch_bounds__(256) void f32_to_bf16_kernel(
    const float4* __restrict__ in, uint4* __restrict__ out, int n8)
{
    int i = blockIdx.x * 256 + threadIdx.x;
    if (i >= n8) return;
    float4 a = in[i * 2];
    float4 b = in[i * 2 + 1];
    float v[8] = {a.x, a.y, a.z, a.w, b.x, b.y, b.z, b.w};
    unsigned r[4];
#pragma unroll
    for (int j = 0; j < 4; ++j)
        r[j] = (unsigned)bf16_rne(v[j * 2]) | ((unsigned)bf16_rne(v[j * 2 + 1]) << 16);
    out[i] = make_uint4(r[0], r[1], r[2], r[3]);
}

// ---------------- weight convert: W[k][n] fp32 -> Wt_h/Wt_l[n][k] bf16 -----

__global__ __launch_bounds__(256) void conv_weights_kernel(
    const float* __restrict__ W0, const float* __restrict__ W1,
    const float* __restrict__ W2, const float* __restrict__ W3,
    unsigned short* __restrict__ Wh, unsigned short* __restrict__ Wl)
{
    int m   = blockIdx.x >> 6;                       // 64 blocks per matrix
    int idx = (blockIdx.x & 63) * 256 + threadIdx.x; // 0..16383
    const float* W = (m == 0) ? W0 : (m == 1) ? W1 : (m == 2) ? W2 : W3;
    int k = idx >> 7, n = idx & 127;
    float v = W[idx];
    unsigned short hh = bf16_rne(v);
    float hf = __uint_as_float(((unsigned)hh) << 16);
    unsigned short ll = bf16_rne(v - hf);
    Wh[m * 16384 + n * 128 + k] = hh;
    Wl[m * 16384 + n * 128 + k] = ll;
}

// ---------------- CSR build ------------------------------------------------

__global__ __launch_bounds__(256) void hist_part_kernel(
    const int* __restrict__ dst, int* __restrict__ counts,
    int n_edges, int n_nodes)
{
    const int p      = blockIdx.x & (NPART - 1);
    const int chunk  = blockIdx.x >> 3;
    const int pstart = (int)(((long long)n_nodes * p)       / NPART);
    const int pend   = (int)(((long long)n_nodes * (p + 1)) / NPART);

    int e0 = chunk * (256 * 4) + threadIdx.x * 4;
    if (e0 >= n_edges) return;
    if (e0 + 3 < n_edges) {
        int4 d = *(const int4*)(dst + e0);
        if (d.x >= pstart && d.x < pend) atomicAdd(&counts[d.x], 1);
        if (d.y >= pstart && d.y < pend) atomicAdd(&counts[d.y], 1);
        if (d.z >= pstart && d.z < pend) atomicAdd(&counts[d.z], 1);
        if (d.w >= pstart && d.w < pend) atomicAdd(&counts[d.w], 1);
    } else {
        for (int e = e0; e < n_edges; ++e) {
            int d = dst[e];
            if (d >= pstart && d < pend) atomicAdd(&counts[d], 1);
        }
    }
}

__global__ __launch_bounds__(256) void scan_phaseA(
    const int* __restrict__ counts, int* __restrict__ block_sums, int n)
{
    __shared__ int s[256];
    int i = blockIdx.x * 256 + threadIdx.x;
    s[threadIdx.x] = (i < n) ? counts[i] : 0;
    __syncthreads();
    for (int off = 128; off > 0; off >>= 1) {
        if (threadIdx.x < off) s[threadIdx.x] += s[threadIdx.x + off];
        __syncthreads();
    }
    if (threadIdx.x == 0) block_sums[blockIdx.x] = s[0];
}

__global__ __launch_bounds__(256) void scan_phaseB(int* __restrict__ block_sums, int nb)
{
    __shared__ int s[256];
    int v = (threadIdx.x < nb) ? block_sums[threadIdx.x] : 0;
    s[threadIdx.x] = v;
    __syncthreads();
    for (int off = 1; off < 256; off <<= 1) {
        int t = (threadIdx.x >= off) ? s[threadIdx.x - off] : 0;
        __syncthreads();
        s[threadIdx.x] += t;
        __syncthreads();
    }
    if (threadIdx.x < nb) block_sums[threadIdx.x] = s[threadIdx.x] - v;  // exclusive
}

__global__ __launch_bounds__(256) void scan_phaseC(
    const int* __restrict__ counts, const int* __restrict__ block_sums,
    int* __restrict__ row_start, int* __restrict__ cursor, int n, int n_edges)
{
    __shared__ int s[256];
    int i = blockIdx.x * 256 + threadIdx.x;
    int v = (i < n) ? counts[i] : 0;
    s[threadIdx.x] = v;
    __syncthreads();
    for (int off = 1; off < 256; off <<= 1) {
        int t = (threadIdx.x >= off) ? s[threadIdx.x - off] : 0;
        __syncthreads();
        s[threadIdx.x] += t;
        __syncthreads();
    }
    if (i < n) {
        int rs = s[threadIdx.x] - v + block_sums[blockIdx.x];
        row_start[i] = rs;
        cursor[i] = rs;
    }
    if (blockIdx.x == 0 && threadIdx.x == 0) row_start[n] = n_edges;
}

__global__ __launch_bounds__(256) void fill_part_kernel(
    const int* __restrict__ src, const int* __restrict__ dst,
    int* __restrict__ cursor, int* __restrict__ csr_src,
    int n_edges, int n_nodes)
{
    const int p      = blockIdx.x & (NPART - 1);
    const int chunk  = blockIdx.x >> 3;
    const int pstart = (int)(((long long)n_nodes * p)       / NPART);
    const int pend   = (int)(((long long)n_nodes * (p + 1)) / NPART);

    int e0 = chunk * (256 * 4) + threadIdx.x * 4;
    if (e0 >= n_edges) return;
    if (e0 + 3 < n_edges) {
        int4 d = *(const int4*)(dst + e0);
        int4 s = *(const int4*)(src + e0);
        if (d.x >= pstart && d.x < pend) csr_src[atomicAdd(&cursor[d.x], 1)] = s.x;
        if (d.y >= pstart && d.y < pend) csr_src[atomicAdd(&cursor[d.y], 1)] = s.y;
        if (d.z >= pstart && d.z < pend) csr_src[atomicAdd(&cursor[d.z], 1)] = s.z;
        if (d.w >= pstart && d.w < pend) csr_src[atomicAdd(&cursor[d.w], 1)] = s.w;
    } else {
        for (int e = e0; e < n_edges; ++e) {
            int d = dst[e];
            if (d >= pstart && d < pend) csr_src[atomicAdd(&cursor[d], 1)] = src[e];
        }
    }
}

// ---------------- gather aggregation (bf16 neighbors, fp32 self/acc) -------

__device__ __forceinline__ void add_row8(float acc[8], uint4 r) {
    union { unsigned u; float f; } c;
    c.u = r.x << 16;         acc[0] += c.f;
    c.u = r.x & 0xffff0000u; acc[1] += c.f;
    c.u = r.y << 16;         acc[2] += c.f;
    c.u = r.y & 0xffff0000u; acc[3] += c.f;
    c.u = r.z << 16;         acc[4] += c.f;
    c.u = r.z & 0xffff0000u; acc[5] += c.f;
    c.u = r.w << 16;         acc[6] += c.f;
    c.u = r.w & 0xffff0000u; acc[7] += c.f;
}

__global__ __launch_bounds__(256) void gather_agg_bf16_kernel(
    const float* __restrict__ xf,    // fp32 rows (self term)
    const uint4* __restrict__ xb,    // bf16 rows, 16 uint4/row
    const int* __restrict__ row_start, const int* __restrict__ csr_src,
    float* __restrict__ out, int n_nodes)
{
    int t = blockIdx.x * 256 + threadIdx.x;
    int node = t >> 4;
    int lane = t & 15;
    if (node >= n_nodes) return;
    int lo = row_start[node];
    int hi = row_start[node + 1];

    const f32x4* xfr = (const f32x4*)(xf + (size_t)node * IN_DIM + lane * 8);
    f32x4 a0 = __builtin_nontemporal_load(xfr);
    f32x4 a1 = __builtin_nontemporal_load(xfr + 1);
    float acc[8] = {a0.x, a0.y, a0.z, a0.w, a1.x, a1.y, a1.z, a1.w};

    int e = lo;
    for (; e + 3 < hi; e += 4) {
        int s0 = csr_src[e];
        int s1 = csr_src[e + 1];
        int s2 = csr_src[e + 2];
        int s3 = csr_src[e + 3];
        uint4 r0 = xb[(size_t)s0 * 16 + lane];
        uint4 r1 = xb[(size_t)s1 * 16 + lane];
        uint4 r2 = xb[(size_t)s2 * 16 + lane];
        uint4 r3 = xb[(size_t)s3 * 16 + lane];
        add_row8(acc, r0);
        add_row8(acc, r1);
        add_row8(acc, r2);
        add_row8(acc, r3);
    }
    for (; e < hi; ++e) {
        uint4 r = xb[(size_t)csr_src[e] * 16 + lane];
        add_row8(acc, r);
    }

    f32x4 o0 = {acc[0], acc[1], acc[2], acc[3]};
    f32x4 o1 = {acc[4], acc[5], acc[6], acc[7]};
    f32x4* op = (f32x4*)(out + (size_t)node * IN_DIM + lane * 8);
    __builtin_nontemporal_store(o0, op);
    __builtin_nontemporal_store(o1, op + 1);
}

// ---------------- split-bf16 MFMA GEMM, barrier-free -----------------------
// C[M x 128] = relu(A @ W + bias) via Ah@Wh + Al@Wh + Ah@Wl.
// One wave per 16 rows. A fragment: lane reads A[row0+l15][k0+quad*8 ..+8)
// straight from global (two float4), converts to bf16 hi/lo in regs.
// W fragment: lane reads Wt[ct*16+l15][k0+quad*8 ..+8) (bf16x8, L2-hot).
// No LDS, no barriers; 8 independent acc tiles for load/MFMA overlap.
__global__ __launch_bounds__(256) void gemm128_mfma_kernel(
    const float* __restrict__ A,
    const unsigned short* __restrict__ Wt_h,  // [n][k] bf16 hi
    const unsigned short* __restrict__ Wt_l,  // [n][k] bf16 lo
    const float* __restrict__ bias,
    float* __restrict__ C, int M)
{
    const int lane = threadIdx.x & 63;
    const int wid  = (blockIdx.x * 256 + threadIdx.x) >> 6;  // global wave id
    const int l15  = lane & 15;
    const int quad = lane >> 4;
    const int row0 = wid * 16;
    if (row0 >= M) return;

    const int arow = row0 + l15;
    const float* aptr = A + (size_t)((arow < M) ? arow : (M - 1)) * IN_DIM + quad * 8;
    const unsigned short* whp = Wt_h + l15 * IN_DIM + quad * 8;
    const unsigned short* wlp = Wt_l + l15 * IN_DIM + quad * 8;

    f32x4 acc[8];
#pragma unroll
    for (int ct = 0; ct < 8; ++ct) acc[ct] = {0.f, 0.f, 0.f, 0.f};

#pragma unroll
    for (int k0 = 0; k0 < IN_DIM; k0 += 32) {
        f32x4 a0 = *(const f32x4*)(aptr + k0);
        f32x4 a1 = *(const f32x4*)(aptr + k0 + 4);
        float v[8] = {a0.x, a0.y, a0.z, a0.w, a1.x, a1.y, a1.z, a1.w};
        unsigned short h[8], l[8];
#pragma unroll
        for (int j = 0; j < 8; ++j) {
            unsigned short hh = bf16_rne(v[j]);
            h[j] = hh;
            l[j] = bf16_rne(v[j] - __uint_as_float(((unsigned)hh) << 16));
        }
        bf16x8 ah = *(const bf16x8*)h;
        bf16x8 al = *(const bf16x8*)l;
#pragma unroll
        for (int ct = 0; ct < 8; ++ct) {
            bf16x8 wh = *(const bf16x8*)(whp + ct * 16 * IN_DIM + k0);
            bf16x8 wl = *(const bf16x8*)(wlp + ct * 16 * IN_DIM + k0);
            acc[ct] = __builtin_amdgcn_mfma_f32_16x16x32_bf16(ah, wh, acc[ct], 0, 0, 0);
            acc[ct] = __builtin_amdgcn_mfma_f32_16x16x32_bf16(al, wh, acc[ct], 0, 0, 0);
            acc[ct] = __builtin_amdgcn_mfma_f32_16x16x32_bf16(ah, wl, acc[ct], 0, 0, 0);
        }
    }

    // epilogue: bias + relu; C/D layout col=l15, row=quad*4+reg
    const int rbase = row0 + quad * 4;
#pragma unroll
    for (int ct = 0; ct < 8; ++ct) {
        int col = ct * 16 + l15;
        float b = bias[col];
#pragma unroll
        for (int r = 0; r < 4; ++r) {
            int row = rbase + r;
            if (row < M)
                C[(size_t)row * IN_DIM + col] = fmaxf(acc[ct][r] + b, 0.f);
        }
    }
}

// ---------------- pool + heads ---------------------------------------------

__device__ __forceinline__ int lower_bound_i(const int* __restrict__ a, int n, int v) {
    int lo = 0, hi = n;
    while (lo < hi) {
        int mid = (lo + hi) >> 1;
        if (a[mid] < v) lo = mid + 1; else hi = mid;
    }
    return lo;
}

__global__ __launch_bounds__(128) void pool_kernel(
    const float* __restrict__ h, const int* __restrict__ batch,
    float* __restrict__ pooled, int n_nodes, int n_graphs)
{
    int g = blockIdx.x;
    int lo = lower_bound_i(batch, n_nodes, g);
    int hi = lower_bound_i(batch, n_nodes, g + 1);
    int j = threadIdx.x;
    float acc = 0.f;
    for (int i = lo; i < hi; ++i)
        acc += h[(size_t)i * IN_DIM + j];
    float cnt = (float)(hi - lo);
    pooled[(size_t)g * IN_DIM + j] = acc / fmaxf(cnt, 1.0f);
}

__global__ __launch_bounds__(64) void head_kernel(
    const float* __restrict__ pooled,
    const float* __restrict__ Ws,  const float* __restrict__ bs,
    const float* __restrict__ WlS, const float* __restrict__ blS,
    const float* __restrict__ WlP, const float* __restrict__ blP,
    const float* __restrict__ WnR, const float* __restrict__ bnR,
    float* __restrict__ out, int n_graphs)
{
    int g = blockIdx.x;
    int j = threadIdx.x;
    const float* p = pooled + (size_t)g * IN_DIM;
    float acc = bs[j];
#pragma unroll 8
    for (int k = 0; k < IN_DIM; ++k)
        acc = fmaf(p[k], Ws[k * 64 + j], acc);
    float gj = fmaxf(acc, 0.f);
    float s1 = gj * WlS[j];
    float s2 = gj * WlP[j];
    float s3 = gj * WnR[j];
#pragma unroll
    for (int off = 32; off > 0; off >>= 1) {
        s1 += __shfl_down(s1, off);
        s2 += __shfl_down(s2, off);
        s3 += __shfl_down(s3, off);
    }
    if (j == 0) {
        out[g]                = s1 + blS[0];
        out[n_graphs + g]     = s2 + blP[0];
        out[2 * n_graphs + g] = s3 + bnR[0];
    }
}

// ---------------- launch ---------------------------------------------------

extern "C" void kernel_launch(void* const* d_in, const int* in_sizes, int n_in,
                              void* d_out, int out_size, void* d_ws, size_t ws_size,
                              hipStream_t stream)
{
    const float* x   = (const float*)d_in[0];
    const int*   ei  = (const int*)d_in[1];
    const int*   bat = (const int*)d_in[2];
    const float* W1a = (const float*)d_in[3];
    const float* b1a = (const float*)d_in[4];
    const float* W1b = (const float*)d_in[5];
    const float* b1b = (const float*)d_in[6];
    const float* W2a = (const float*)d_in[7];
    const float* b2a = (const float*)d_in[8];
    const float* W2b = (const float*)d_in[9];
    const float* b2b = (const float*)d_in[10];
    const float* Ws  = (const float*)d_in[11];
    const float* bs  = (const float*)d_in[12];
    const float* WlS = (const float*)d_in[13];
    const float* blS = (const float*)d_in[14];
    const float* WlP = (const float*)d_in[15];
    const float* blP = (const float*)d_in[16];
    const float* WnR = (const float*)d_in[17];
    const float* bnR = (const float*)d_in[18];

    const int n_nodes  = in_sizes[0] / IN_DIM;
    const int n_edges  = in_sizes[1] / 2;
    const int n_graphs = out_size / 3;
    const int* src = ei;
    const int* dst = ei + n_edges;

    const size_t node_elems   = (size_t)n_nodes * IN_DIM;
    const size_t pooled_elems = (size_t)n_graphs * IN_DIM;

    float* h1     = (float*)d_ws;
    float* buf2   = h1   + node_elems;
    float* bufA   = buf2 + node_elems;          // gather output (x + agg)
    float* pooled = bufA + node_elems;
    int* row_start = (int*)(pooled + pooled_elems);   // n_nodes + 1
    int* cursor    = row_start + (n_nodes + 1);       // n_nodes (also histogram)
    int* csr_src   = cursor + n_nodes;                // n_edges
    unsigned short* wt_h = (unsigned short*)(csr_src + n_edges);  // 4 * 16384
    unsigned short* wt_l = wt_h + 4 * 16384;

    // bf16 mirror aliases h1 (dead at convert time; consumed before h1 write)
    uint4* xb = (uint4*)h1;

    const int eblocks4 = (n_edges + 1023) / 1024;
    const int nblocks256 = (n_nodes + 255) / 256;
    const int gatherblocks = (int)(((size_t)n_nodes * 16 + 255) / 256);
    const int gemmblocks = ((n_nodes + 15) / 16 + 3) / 4;   // 4 waves/block
    const int partblocks = NPART * eblocks4;
    const int n8 = (int)(node_elems / 8);
    const int cvtblocks = (n8 + 255) / 256;

    // ---- weight conversion + CSR build ----
    conv_weights_kernel<<<256, 256, 0, stream>>>(W1a, W1b, W2a, W2b, wt_h, wt_l);
    hipMemsetAsync(cursor, 0, (size_t)n_nodes * sizeof(int), stream);
    hist_part_kernel<<<partblocks, 256, 0, stream>>>(dst, cursor, n_edges, n_nodes);
    scan_phaseA<<<nblocks256, 256, 0, stream>>>(cursor, csr_src /*scratch*/, n_nodes);
    scan_phaseB<<<1, 256, 0, stream>>>(csr_src, nblocks256);
    scan_phaseC<<<nblocks256, 256, 0, stream>>>(cursor, csr_src, row_start,
                                                cursor, n_nodes, n_edges);
    fill_part_kernel<<<partblocks, 256, 0, stream>>>(src, dst, cursor, csr_src,
                                                     n_edges, n_nodes);

    // ---- layer 1 ----
    f32_to_bf16_kernel<<<cvtblocks, 256, 0, stream>>>((const float4*)x, xb, n8);
    gather_agg_bf16_kernel<<<gatherblocks, 256, 0, stream>>>(
        x, xb, row_start, csr_src, bufA, n_nodes);
    gemm128_mfma_kernel<<<gemmblocks, 256, 0, stream>>>(
        bufA, wt_h,             wt_l,             b1a, h1,   n_nodes);
    gemm128_mfma_kernel<<<gemmblocks, 256, 0, stream>>>(
        h1,   wt_h + 16384,     wt_l + 16384,     b1b, buf2, n_nodes);

    // ---- layer 2 ----
    f32_to_bf16_kernel<<<cvtblocks, 256, 0, stream>>>((const float4*)buf2, xb, n8);
    gather_agg_bf16_kernel<<<gatherblocks, 256, 0, stream>>>(
        buf2, xb, row_start, csr_src, bufA, n_nodes);
    gemm128_mfma_kernel<<<gemmblocks, 256, 0, stream>>>(
        bufA, wt_h + 2 * 16384, wt_l + 2 * 16384, b2a, h1,   n_nodes);
    gemm128_mfma_kernel<<<gemmblocks, 256, 0, stream>>>(
        h1,   wt_h + 3 * 16384, wt_l + 3 * 16384, b2b, buf2, n_nodes);

    // ---- pool + heads ----
    pool_kernel<<<n_graphs, 128, 0, stream>>>(buf2, bat, pooled, n_nodes, n_graphs);
    head_kernel<<<n_graphs, 64, 0, stream>>>(pooled, Ws, bs, WlS, blS, WlP, blP,
                                             WnR, bnR, (float*)d_out, n_graphs);
}

// Round 8
// 539.691 us; speedup vs baseline: 1.0501x; 1.0501x over previous
//
#include <hip/hip_runtime.h>
#include <hip/hip_bf16.h>

// ---------------------------------------------------------------------------
// GIN multi-task forward on MI355X.
// R8: fused MLP kernel — both GEMMs of each GIN MLP in one dispatch. h stays
// on-chip (LDS round-trip converts MFMA C-layout -> A-fragment layout).
// Split-bf16 (hi/lo) everywhere => fp32-grade accuracy. MLP1 epilogue also
// writes the bf16 mirror for layer-2's gather (drops one convert kernel).
// 16 dispatches -> 13; removes 140 MB of intermediate traffic.
// ---------------------------------------------------------------------------

#define IN_DIM 128
#define NPART 8          // one partition per XCD

typedef float  f32x4  __attribute__((ext_vector_type(4)));
typedef short  bf16x4 __attribute__((ext_vector_type(4)));
typedef short  bf16x8 __attribute__((ext_vector_type(8)));

__device__ __forceinline__ unsigned short bf16_rne(float v) {
    unsigned u = __float_as_uint(v);
    unsigned t = u + 0x7fffu + ((u >> 16) & 1u);
    return (unsigned short)(t >> 16);
}

// ---------------- fp32 -> bf16 convert (RNE), 8 elems/thread ---------------

__global__ __launch_bounds__(256) void f32_to_bf16_kernel(
    const float4* __restrict__ in, uint4* __restrict__ out, int n8)
{
    int i = blockIdx.x * 256 + threadIdx.x;
    if (i >= n8) return;
    float4 a = in[i * 2];
    float4 b = in[i * 2 + 1];
    float v[8] = {a.x, a.y, a.z, a.w, b.x, b.y, b.z, b.w};
    unsigned r[4];
#pragma unroll
    for (int j = 0; j < 4; ++j)
        r[j] = (unsigned)bf16_rne(v[j * 2]) | ((unsigned)bf16_rne(v[j * 2 + 1]) << 16);
    out[i] = make_uint4(r[0], r[1], r[2], r[3]);
}

// ---------------- weight convert: W[k][n] fp32 -> Wt_h/Wt_l[n][k] bf16 -----

__global__ __launch_bounds__(256) void conv_weights_kernel(
    const float* __restrict__ W0, const float* __restrict__ W1,
    const float* __restrict__ W2, const float* __restrict__ W3,
    unsigned short* __restrict__ Wh, unsigned short* __restrict__ Wl)
{
    int m   = blockIdx.x >> 6;                       // 64 blocks per matrix
    int idx = (blockIdx.x & 63) * 256 + threadIdx.x; // 0..16383
    const float* W = (m == 0) ? W0 : (m == 1) ? W1 : (m == 2) ? W2 : W3;
    int k = idx >> 7, n = idx & 127;
    float v = W[idx];
    unsigned short hh = bf16_rne(v);
    float hf = __uint_as_float(((unsigned)hh) << 16);
    unsigned short ll = bf16_rne(v - hf);
    Wh[m * 16384 + n * 128 + k] = hh;
    Wl[m * 16384 + n * 128 + k] = ll;
}

// ---------------- CSR build ------------------------------------------------

__global__ __launch_bounds__(256) void hist_part_kernel(
    const int* __restrict__ dst, int* __restrict__ counts,
    int n_edges, int n_nodes)
{
    const int p      = blockIdx.x & (NPART - 1);
    const int chunk  = blockIdx.x >> 3;
    const int pstart = (int)(((long long)n_nodes * p)       / NPART);
    const int pend   = (int)(((long long)n_nodes * (p + 1)) / NPART);

    int e0 = chunk * (256 * 4) + threadIdx.x * 4;
    if (e0 >= n_edges) return;
    if (e0 + 3 < n_edges) {
        int4 d = *(const int4*)(dst + e0);
        if (d.x >= pstart && d.x < pend) atomicAdd(&counts[d.x], 1);
        if (d.y >= pstart && d.y < pend) atomicAdd(&counts[d.y], 1);
        if (d.z >= pstart && d.z < pend) atomicAdd(&counts[d.z], 1);
        if (d.w >= pstart && d.w < pend) atomicAdd(&counts[d.w], 1);
    } else {
        for (int e = e0; e < n_edges; ++e) {
            int d = dst[e];
            if (d >= pstart && d < pend) atomicAdd(&counts[d], 1);
        }
    }
}

__global__ __launch_bounds__(256) void scan_phaseA(
    const int* __restrict__ counts, int* __restrict__ block_sums, int n)
{
    __shared__ int s[256];
    int i = blockIdx.x * 256 + threadIdx.x;
    s[threadIdx.x] = (i < n) ? counts[i] : 0;
    __syncthreads();
    for (int off = 128; off > 0; off >>= 1) {
        if (threadIdx.x < off) s[threadIdx.x] += s[threadIdx.x + off];
        __syncthreads();
    }
    if (threadIdx.x == 0) block_sums[blockIdx.x] = s[0];
}

__global__ __launch_bounds__(256) void scan_phaseB(int* __restrict__ block_sums, int nb)
{
    __shared__ int s[256];
    int v = (threadIdx.x < nb) ? block_sums[threadIdx.x] : 0;
    s[threadIdx.x] = v;
    __syncthreads();
    for (int off = 1; off < 256; off <<= 1) {
        int t = (threadIdx.x >= off) ? s[threadIdx.x - off] : 0;
        __syncthreads();
        s[threadIdx.x] += t;
        __syncthreads();
    }
    if (threadIdx.x < nb) block_sums[threadIdx.x] = s[threadIdx.x] - v;  // exclusive
}

__global__ __launch_bounds__(256) void scan_phaseC(
    const int* __restrict__ counts, const int* __restrict__ block_sums,
    int* __restrict__ row_start, int* __restrict__ cursor, int n, int n_edges)
{
    __shared__ int s[256];
    int i = blockIdx.x * 256 + threadIdx.x;
    int v = (i < n) ? counts[i] : 0;
    s[threadIdx.x] = v;
    __syncthreads();
    for (int off = 1; off < 256; off <<= 1) {
        int t = (threadIdx.x >= off) ? s[threadIdx.x - off] : 0;
        __syncthreads();
        s[threadIdx.x] += t;
        __syncthreads();
    }
    if (i < n) {
        int rs = s[threadIdx.x] - v + block_sums[blockIdx.x];
        row_start[i] = rs;
        cursor[i] = rs;
    }
    if (blockIdx.x == 0 && threadIdx.x == 0) row_start[n] = n_edges;
}

__global__ __launch_bounds__(256) void fill_part_kernel(
    const int* __restrict__ src, const int* __restrict__ dst,
    int* __restrict__ cursor, int* __restrict__ csr_src,
    int n_edges, int n_nodes)
{
    const int p      = blockIdx.x & (NPART - 1);
    const int chunk  = blockIdx.x >> 3;
    const int pstart = (int)(((long long)n_nodes * p)       / NPART);
    const int pend   = (int)(((long long)n_nodes * (p + 1)) / NPART);

    int e0 = chunk * (256 * 4) + threadIdx.x * 4;
    if (e0 >= n_edges) return;
    if (e0 + 3 < n_edges) {
        int4 d = *(const int4*)(dst + e0);
        int4 s = *(const int4*)(src + e0);
        if (d.x >= pstart && d.x < pend) csr_src[atomicAdd(&cursor[d.x], 1)] = s.x;
        if (d.y >= pstart && d.y < pend) csr_src[atomicAdd(&cursor[d.y], 1)] = s.y;
        if (d.z >= pstart && d.z < pend) csr_src[atomicAdd(&cursor[d.z], 1)] = s.z;
        if (d.w >= pstart && d.w < pend) csr_src[atomicAdd(&cursor[d.w], 1)] = s.w;
    } else {
        for (int e = e0; e < n_edges; ++e) {
            int d = dst[e];
            if (d >= pstart && d < pend) csr_src[atomicAdd(&cursor[d], 1)] = src[e];
        }
    }
}

// ---------------- gather aggregation (bf16 neighbors, fp32 self/acc) -------

__device__ __forceinline__ void add_row8(float acc[8], uint4 r) {
    union { unsigned u; float f; } c;
    c.u = r.x << 16;         acc[0] += c.f;
    c.u = r.x & 0xffff0000u; acc[1] += c.f;
    c.u = r.y << 16;         acc[2] += c.f;
    c.u = r.y & 0xffff0000u; acc[3] += c.f;
    c.u = r.z << 16;         acc[4] += c.f;
    c.u = r.z & 0xffff0000u; acc[5] += c.f;
    c.u = r.w << 16;         acc[6] += c.f;
    c.u = r.w & 0xffff0000u; acc[7] += c.f;
}

__global__ __launch_bounds__(256) void gather_agg_bf16_kernel(
    const float* __restrict__ xf,    // fp32 rows (self term)
    const uint4* __restrict__ xb,    // bf16 rows, 16 uint4/row
    const int* __restrict__ row_start, const int* __restrict__ csr_src,
    float* __restrict__ out, int n_nodes)
{
    int t = blockIdx.x * 256 + threadIdx.x;
    int node = t >> 4;
    int lane = t & 15;
    if (node >= n_nodes) return;
    int lo = row_start[node];
    int hi = row_start[node + 1];

    const f32x4* xfr = (const f32x4*)(xf + (size_t)node * IN_DIM + lane * 8);
    f32x4 a0 = __builtin_nontemporal_load(xfr);
    f32x4 a1 = __builtin_nontemporal_load(xfr + 1);
    float acc[8] = {a0.x, a0.y, a0.z, a0.w, a1.x, a1.y, a1.z, a1.w};

    int e = lo;
    for (; e + 3 < hi; e += 4) {
        int s0 = csr_src[e];
        int s1 = csr_src[e + 1];
        int s2 = csr_src[e + 2];
        int s3 = csr_src[e + 3];
        uint4 r0 = xb[(size_t)s0 * 16 + lane];
        uint4 r1 = xb[(size_t)s1 * 16 + lane];
        uint4 r2 = xb[(size_t)s2 * 16 + lane];
        uint4 r3 = xb[(size_t)s3 * 16 + lane];
        add_row8(acc, r0);
        add_row8(acc, r1);
        add_row8(acc, r2);
        add_row8(acc, r3);
    }
    for (; e < hi; ++e) {
        uint4 r = xb[(size_t)csr_src[e] * 16 + lane];
        add_row8(acc, r);
    }

    f32x4 o0 = {acc[0], acc[1], acc[2], acc[3]};
    f32x4 o1 = {acc[4], acc[5], acc[6], acc[7]};
    f32x4* op = (f32x4*)(out + (size_t)node * IN_DIM + lane * 8);
    __builtin_nontemporal_store(o0, op);
    __builtin_nontemporal_store(o1, op + 1);
}

// ---------------- fused MLP: relu(relu(A@Wa+ba)@Wb+bb) ---------------------
// Block = 64 rows, 4 waves, wave w owns rows [w*16, w*16+16).
// Stage 1: split-bf16 A from global, W frags from L2; 8 col-tiles.
// Epilogue 1: h=relu(+ba), split hi/lo, to LDS [64][HSTRIDE] (C-layout ->
// A-frag layout transform). One __syncthreads.
// Stage 2: A frags from LDS (b64 pairs, stride 264B: epilogue writes
// conflict-free, reads <=4-way), W frags from L2; epilogue relu(+bb) -> C
// (+ optional bf16 mirror for the next gather).
#define HSTRIDE 132      // ushort elems; 264B row: LDS-conflict-benign

template <bool EMIT_BF16>
__global__ __launch_bounds__(256) void fused_mlp_kernel(
    const float* __restrict__ A,
    const unsigned short* __restrict__ Wa_h, const unsigned short* __restrict__ Wa_l,
    const float* __restrict__ ba,
    const unsigned short* __restrict__ Wb_h, const unsigned short* __restrict__ Wb_l,
    const float* __restrict__ bb,
    float* __restrict__ C, unsigned short* __restrict__ Cb, int M)
{
    __shared__ __align__(16) unsigned short Hh[64][HSTRIDE];
    __shared__ __align__(16) unsigned short Hl[64][HSTRIDE];

    const int t    = threadIdx.x;
    const int wave = t >> 6;
    const int lane = t & 63;
    const int l15  = lane & 15;
    const int quad = lane >> 4;
    const int wrow0 = wave * 16;                 // wave's row base within block
    const int row0  = blockIdx.x * 64 + wrow0;   // global

    f32x4 acc[8];
#pragma unroll
    for (int ct = 0; ct < 8; ++ct) acc[ct] = {0.f, 0.f, 0.f, 0.f};

    // ---- stage 1: A (global fp32, split) @ Wa ----
    {
        const int arow = row0 + l15;
        const float* aptr = A + (size_t)((arow < M) ? arow : (M - 1)) * IN_DIM + quad * 8;
#pragma unroll
        for (int k0 = 0; k0 < IN_DIM; k0 += 32) {
            f32x4 a0 = *(const f32x4*)(aptr + k0);
            f32x4 a1 = *(const f32x4*)(aptr + k0 + 4);
            float v[8] = {a0.x, a0.y, a0.z, a0.w, a1.x, a1.y, a1.z, a1.w};
            unsigned short h[8], l[8];
#pragma unroll
            for (int j = 0; j < 8; ++j) {
                unsigned short hh = bf16_rne(v[j]);
                h[j] = hh;
                l[j] = bf16_rne(v[j] - __uint_as_float(((unsigned)hh) << 16));
            }
            bf16x8 ah = *(const bf16x8*)h;
            bf16x8 al = *(const bf16x8*)l;
#pragma unroll
            for (int ct = 0; ct < 8; ++ct) {
                const unsigned short* wp = Wa_h + (size_t)(ct * 16 + l15) * IN_DIM + k0 + quad * 8;
                const unsigned short* lp = Wa_l + (size_t)(ct * 16 + l15) * IN_DIM + k0 + quad * 8;
                bf16x8 wh = *(const bf16x8*)wp;
                bf16x8 wl = *(const bf16x8*)lp;
                acc[ct] = __builtin_amdgcn_mfma_f32_16x16x32_bf16(ah, wh, acc[ct], 0, 0, 0);
                acc[ct] = __builtin_amdgcn_mfma_f32_16x16x32_bf16(al, wh, acc[ct], 0, 0, 0);
                acc[ct] = __builtin_amdgcn_mfma_f32_16x16x32_bf16(ah, wl, acc[ct], 0, 0, 0);
            }
        }
    }

    // ---- epilogue 1: h = relu(acc + ba) -> LDS (split bf16) ----
#pragma unroll
    for (int ct = 0; ct < 8; ++ct) {
        int col = ct * 16 + l15;
        float b = ba[col];
#pragma unroll
        for (int r = 0; r < 4; ++r) {
            int rl = wrow0 + quad * 4 + r;
            float v = fmaxf(acc[ct][r] + b, 0.f);
            unsigned short hh = bf16_rne(v);
            Hh[rl][col] = hh;
            Hl[rl][col] = bf16_rne(v - __uint_as_float(((unsigned)hh) << 16));
        }
        acc[ct] = {0.f, 0.f, 0.f, 0.f};
    }
    __syncthreads();

    // ---- stage 2: h (LDS, split) @ Wb ----
#pragma unroll
    for (int k0 = 0; k0 < IN_DIM; k0 += 32) {
        const int hk = k0 + quad * 8;
        bf16x4 h0 = *(const bf16x4*)&Hh[wrow0 + l15][hk];
        bf16x4 h1 = *(const bf16x4*)&Hh[wrow0 + l15][hk + 4];
        bf16x4 l0 = *(const bf16x4*)&Hl[wrow0 + l15][hk];
        bf16x4 l1 = *(const bf16x4*)&Hl[wrow0 + l15][hk + 4];
        bf16x8 ah = __builtin_shufflevector(h0, h1, 0, 1, 2, 3, 4, 5, 6, 7);
        bf16x8 al = __builtin_shufflevector(l0, l1, 0, 1, 2, 3, 4, 5, 6, 7);
#pragma unroll
        for (int ct = 0; ct < 8; ++ct) {
            const unsigned short* wp = Wb_h + (size_t)(ct * 16 + l15) * IN_DIM + k0 + quad * 8;
            const unsigned short* lp = Wb_l + (size_t)(ct * 16 + l15) * IN_DIM + k0 + quad * 8;
            bf16x8 wh = *(const bf16x8*)wp;
            bf16x8 wl = *(const bf16x8*)lp;
            acc[ct] = __builtin_amdgcn_mfma_f32_16x16x32_bf16(ah, wh, acc[ct], 0, 0, 0);
            acc[ct] = __builtin_amdgcn_mfma_f32_16x16x32_bf16(al, wh, acc[ct], 0, 0, 0);
            acc[ct] = __builtin_amdgcn_mfma_f32_16x16x32_bf16(ah, wl, acc[ct], 0, 0, 0);
        }
    }

    // ---- epilogue 2: out = relu(acc + bb) -> C (+ bf16 mirror) ----
    const int rbase = row0 + quad * 4;
#pragma unroll
    for (int ct = 0; ct < 8; ++ct) {
        int col = ct * 16 + l15;
        float b = bb[col];
#pragma unroll
        for (int r = 0; r < 4; ++r) {
            int row = rbase + r;
            if (row < M) {
                float o = fmaxf(acc[ct][r] + b, 0.f);
                C[(size_t)row * IN_DIM + col] = o;
                if (EMIT_BF16)
                    Cb[(size_t)row * IN_DIM + col] = bf16_rne(o);
            }
        }
    }
}

// ---------------- pool + heads ---------------------------------------------

__device__ __forceinline__ int lower_bound_i(const int* __restrict__ a, int n, int v) {
    int lo = 0, hi = n;
    while (lo < hi) {
        int mid = (lo + hi) >> 1;
        if (a[mid] < v) lo = mid + 1; else hi = mid;
    }
    return lo;
}

__global__ __launch_bounds__(128) void pool_kernel(
    const float* __restrict__ h, const int* __restrict__ batch,
    float* __restrict__ pooled, int n_nodes, int n_graphs)
{
    int g = blockIdx.x;
    int lo = lower_bound_i(batch, n_nodes, g);
    int hi = lower_bound_i(batch, n_nodes, g + 1);
    int j = threadIdx.x;
    float acc = 0.f;
    for (int i = lo; i < hi; ++i)
        acc += h[(size_t)i * IN_DIM + j];
    float cnt = (float)(hi - lo);
    pooled[(size_t)g * IN_DIM + j] = acc / fmaxf(cnt, 1.0f);
}

__global__ __launch_bounds__(64) void head_kernel(
    const float* __restrict__ pooled,
    const float* __restrict__ Ws,  const float* __restrict__ bs,
    const float* __restrict__ WlS, const float* __restrict__ blS,
    const float* __restrict__ WlP, const float* __restrict__ blP,
    const float* __restrict__ WnR, const float* __restrict__ bnR,
    float* __restrict__ out, int n_graphs)
{
    int g = blockIdx.x;
    int j = threadIdx.x;
    const float* p = pooled + (size_t)g * IN_DIM;
    float acc = bs[j];
#pragma unroll 8
    for (int k = 0; k < IN_DIM; ++k)
        acc = fmaf(p[k], Ws[k * 64 + j], acc);
    float gj = fmaxf(acc, 0.f);
    float s1 = gj * WlS[j];
    float s2 = gj * WlP[j];
    float s3 = gj * WnR[j];
#pragma unroll
    for (int off = 32; off > 0; off >>= 1) {
        s1 += __shfl_down(s1, off);
        s2 += __shfl_down(s2, off);
        s3 += __shfl_down(s3, off);
    }
    if (j == 0) {
        out[g]                = s1 + blS[0];
        out[n_graphs + g]     = s2 + blP[0];
        out[2 * n_graphs + g] = s3 + bnR[0];
    }
}

// ---------------- launch ---------------------------------------------------

extern "C" void kernel_launch(void* const* d_in, const int* in_sizes, int n_in,
                              void* d_out, int out_size, void* d_ws, size_t ws_size,
                              hipStream_t stream)
{
    const float* x   = (const float*)d_in[0];
    const int*   ei  = (const int*)d_in[1];
    const int*   bat = (const int*)d_in[2];
    const float* W1a = (const float*)d_in[3];
    const float* b1a = (const float*)d_in[4];
    const float* W1b = (const float*)d_in[5];
    const float* b1b = (const float*)d_in[6];
    const float* W2a = (const float*)d_in[7];
    const float* b2a = (const float*)d_in[8];
    const float* W2b = (const float*)d_in[9];
    const float* b2b = (const float*)d_in[10];
    const float* Ws  = (const float*)d_in[11];
    const float* bs  = (const float*)d_in[12];
    const float* WlS = (const float*)d_in[13];
    const float* blS = (const float*)d_in[14];
    const float* WlP = (const float*)d_in[15];
    const float* blP = (const float*)d_in[16];
    const float* WnR = (const float*)d_in[17];
    const float* bnR = (const float*)d_in[18];

    const int n_nodes  = in_sizes[0] / IN_DIM;
    const int n_edges  = in_sizes[1] / 2;
    const int n_graphs = out_size / 3;
    const int* src = ei;
    const int* dst = ei + n_edges;

    const size_t node_elems   = (size_t)n_nodes * IN_DIM;
    const size_t pooled_elems = (size_t)n_graphs * IN_DIM;

    float* xbf    = (float*)d_ws;               // bf16 mirror slot (node_elems/2 used)
    float* buf2   = xbf  + node_elems;
    float* bufA   = buf2 + node_elems;          // gather output (x + agg)
    float* pooled = bufA + node_elems;
    int* row_start = (int*)(pooled + pooled_elems);   // n_nodes + 1
    int* cursor    = row_start + (n_nodes + 1);       // n_nodes (also histogram)
    int* csr_src   = cursor + n_nodes;                // n_edges
    unsigned short* wt_h = (unsigned short*)(csr_src + n_edges);  // 4 * 16384
    unsigned short* wt_l = wt_h + 4 * 16384;

    unsigned short* xb = (unsigned short*)xbf;

    const int eblocks4 = (n_edges + 1023) / 1024;
    const int nblocks256 = (n_nodes + 255) / 256;
    const int gatherblocks = (int)(((size_t)n_nodes * 16 + 255) / 256);
    const int mlpblocks = (n_nodes + 63) / 64;
    const int partblocks = NPART * eblocks4;
    const int n8 = (int)(node_elems / 8);
    const int cvtblocks = (n8 + 255) / 256;

    // ---- weight conversion + CSR build ----
    conv_weights_kernel<<<256, 256, 0, stream>>>(W1a, W1b, W2a, W2b, wt_h, wt_l);
    hipMemsetAsync(cursor, 0, (size_t)n_nodes * sizeof(int), stream);
    hist_part_kernel<<<partblocks, 256, 0, stream>>>(dst, cursor, n_edges, n_nodes);
    scan_phaseA<<<nblocks256, 256, 0, stream>>>(cursor, csr_src /*scratch*/, n_nodes);
    scan_phaseB<<<1, 256, 0, stream>>>(csr_src, nblocks256);
    scan_phaseC<<<nblocks256, 256, 0, stream>>>(cursor, csr_src, row_start,
                                                cursor, n_nodes, n_edges);
    fill_part_kernel<<<partblocks, 256, 0, stream>>>(src, dst, cursor, csr_src,
                                                     n_edges, n_nodes);

    // ---- layer 1 ----
    f32_to_bf16_kernel<<<cvtblocks, 256, 0, stream>>>((const float4*)x, (uint4*)xb, n8);
    gather_agg_bf16_kernel<<<gatherblocks, 256, 0, stream>>>(
        x, (const uint4*)xb, row_start, csr_src, bufA, n_nodes);
    // MLP1: writes buf2 fp32 AND xb bf16 mirror (for layer-2 gather)
    fused_mlp_kernel<true><<<mlpblocks, 256, 0, stream>>>(
        bufA, wt_h, wt_l, b1a, wt_h + 16384, wt_l + 16384, b1b,
        buf2, xb, n_nodes);

    // ---- layer 2 ----
    gather_agg_bf16_kernel<<<gatherblocks, 256, 0, stream>>>(
        buf2, (const uint4*)xb, row_start, csr_src, bufA, n_nodes);
    fused_mlp_kernel<false><<<mlpblocks, 256, 0, stream>>>(
        bufA, wt_h + 2 * 16384, wt_l + 2 * 16384, b2a,
        wt_h + 3 * 16384, wt_l + 3 * 16384, b2b,
        buf2, nullptr, n_nodes);

    // ---- pool + heads ----
    pool_kernel<<<n_graphs, 128, 0, stream>>>(buf2, bat, pooled, n_nodes, n_graphs);
    head_kernel<<<n_graphs, 64, 0, stream>>>(pooled, Ws, bs, WlS, blS, WlP, blP,
                                             WnR, bnR, (float*)d_out, n_graphs);
}

// Round 9
// 504.317 us; speedup vs baseline: 1.1238x; 1.0701x over previous
//
#include <hip/hip_runtime.h>
#include <hip/hip_bf16.h>

// ---------------------------------------------------------------------------
// GIN multi-task forward on MI355X.
// R9: (1) fused MLP with 32 rows/wave (two 16-row tiles sharing W fragments:
// 6 MFMAs per 2 W-loads, 16 indep acc chains) — R8 showed 74us @ Occ 24.7%,
// MfmaUtil 4.9%, VGPR 60 = latency-bound with no ILP. (2) bucket-based CSR
// build: bin edges into 8 dst-range buckets (sequential writes), then hist
// and fill read only their XCD's ~1.6MB bucket -> reads+writes+cursors all
// L2-resident (R8 fill: 65MB WRITE from streaming reads evicting csr lines).
// ---------------------------------------------------------------------------

#define IN_DIM 128
#define NPART 8

typedef float  f32x4  __attribute__((ext_vector_type(4)));
typedef short  bf16x4 __attribute__((ext_vector_type(4)));
typedef short  bf16x8 __attribute__((ext_vector_type(8)));

__device__ __forceinline__ unsigned short bf16_rne(float v) {
    unsigned u = __float_as_uint(v);
    unsigned t = u + 0x7fffu + ((u >> 16) & 1u);
    return (unsigned short)(t >> 16);
}

// ---------------- fp32 -> bf16 convert (RNE), 8 elems/thread ---------------

__global__ __launch_bounds__(256) void f32_to_bf16_kernel(
    const float4* __restrict__ in, uint4* __restrict__ out, int n8)
{
    int i = blockIdx.x * 256 + threadIdx.x;
    if (i >= n8) return;
    float4 a = in[i * 2];
    float4 b = in[i * 2 + 1];
    float v[8] = {a.x, a.y, a.z, a.w, b.x, b.y, b.z, b.w};
    unsigned r[4];
#pragma unroll
    for (int j = 0; j < 4; ++j)
        r[j] = (unsigned)bf16_rne(v[j * 2]) | ((unsigned)bf16_rne(v[j * 2 + 1]) << 16);
    out[i] = make_uint4(r[0], r[1], r[2], r[3]);
}

// ---------------- weight convert: W[k][n] fp32 -> Wt_h/Wt_l[n][k] bf16 -----

__global__ __launch_bounds__(256) void conv_weights_kernel(
    const float* __restrict__ W0, const float* __restrict__ W1,
    const float* __restrict__ W2, const float* __restrict__ W3,
    unsigned short* __restrict__ Wh, unsigned short* __restrict__ Wl)
{
    int m   = blockIdx.x >> 6;
    int idx = (blockIdx.x & 63) * 256 + threadIdx.x;
    const float* W = (m == 0) ? W0 : (m == 1) ? W1 : (m == 2) ? W2 : W3;
    int k = idx >> 7, n = idx & 127;
    float v = W[idx];
    unsigned short hh = bf16_rne(v);
    float hf = __uint_as_float(((unsigned)hh) << 16);
    unsigned short ll = bf16_rne(v - hf);
    Wh[m * 16384 + n * 128 + k] = hh;
    Wl[m * 16384 + n * 128 + k] = ll;
}

// ---------------- CSR build: bucket bin -> hist -> scan -> fill ------------

// Pass 1: bin edges into 8 dst-range buckets. Block-local LDS counts + one
// global cursor reservation per bucket -> bucket writes are contiguous runs.
__global__ __launch_bounds__(256) void bin_kernel(
    const int* __restrict__ src, const int* __restrict__ dst,
    int2* __restrict__ buckets, int* __restrict__ bcur,
    int n_edges, int n_nodes, int cap)
{
    __shared__ int cnt[NPART];
    __shared__ int base[NPART];
    if (threadIdx.x < NPART) cnt[threadIdx.x] = 0;
    __syncthreads();

    int e0 = blockIdx.x * 1024 + threadIdx.x * 4;
    int d[4], s[4], b[4], off[4];
    int ne = 0;
    if (e0 + 3 < n_edges) {
        int4 dv = *(const int4*)(dst + e0);
        int4 sv = *(const int4*)(src + e0);
        d[0] = dv.x; d[1] = dv.y; d[2] = dv.z; d[3] = dv.w;
        s[0] = sv.x; s[1] = sv.y; s[2] = sv.z; s[3] = sv.w;
        ne = 4;
    } else {
        for (int e = e0; e < n_edges; ++e) { d[ne] = dst[e]; s[ne] = src[e]; ++ne; }
    }
    for (int j = 0; j < ne; ++j) {
        b[j] = (int)(((long long)d[j] * NPART) / n_nodes);
        off[j] = atomicAdd(&cnt[b[j]], 1);
    }
    __syncthreads();
    if (threadIdx.x < NPART)
        base[threadIdx.x] = atomicAdd(&bcur[threadIdx.x], cnt[threadIdx.x]);
    __syncthreads();
    for (int j = 0; j < ne; ++j)
        buckets[(size_t)b[j] * cap + base[b[j]] + off[j]] = make_int2(d[j], s[j]);
}

// Pass 2: per-node histogram; XCD p reads only bucket p (L2-resident).
__global__ __launch_bounds__(256) void hist_bucket_kernel(
    const int2* __restrict__ buckets, const int* __restrict__ bcnt,
    int* __restrict__ counts, int cap)
{
    int p = blockIdx.x & (NPART - 1);
    int chunk = blockIdx.x >> 3;
    int n = bcnt[p];
    int i0 = chunk * 1024 + threadIdx.x * 4;
    if (i0 >= n) return;
    const int2* bp = buckets + (size_t)p * cap;
#pragma unroll
    for (int j = 0; j < 4; ++j)
        if (i0 + j < n) atomicAdd(&counts[bp[i0 + j].x], 1);
}

__global__ __launch_bounds__(256) void scan_phaseA(
    const int* __restrict__ counts, int* __restrict__ block_sums, int n)
{
    __shared__ int s[256];
    int i = blockIdx.x * 256 + threadIdx.x;
    s[threadIdx.x] = (i < n) ? counts[i] : 0;
    __syncthreads();
    for (int off = 128; off > 0; off >>= 1) {
        if (threadIdx.x < off) s[threadIdx.x] += s[threadIdx.x + off];
        __syncthreads();
    }
    if (threadIdx.x == 0) block_sums[blockIdx.x] = s[0];
}

__global__ __launch_bounds__(256) void scan_phaseB(int* __restrict__ block_sums, int nb)
{
    __shared__ int s[256];
    int v = (threadIdx.x < nb) ? block_sums[threadIdx.x] : 0;
    s[threadIdx.x] = v;
    __syncthreads();
    for (int off = 1; off < 256; off <<= 1) {
        int t = (threadIdx.x >= off) ? s[threadIdx.x - off] : 0;
        __syncthreads();
        s[threadIdx.x] += t;
        __syncthreads();
    }
    if (threadIdx.x < nb) block_sums[threadIdx.x] = s[threadIdx.x] - v;
}

__global__ __launch_bounds__(256) void scan_phaseC(
    const int* __restrict__ counts, const int* __restrict__ block_sums,
    int* __restrict__ row_start, int* __restrict__ cursor, int n, int n_edges)
{
    __shared__ int s[256];
    int i = blockIdx.x * 256 + threadIdx.x;
    int v = (i < n) ? counts[i] : 0;
    s[threadIdx.x] = v;
    __syncthreads();
    for (int off = 1; off < 256; off <<= 1) {
        int t = (threadIdx.x >= off) ? s[threadIdx.x - off] : 0;
        __syncthreads();
        s[threadIdx.x] += t;
        __syncthreads();
    }
    if (i < n) {
        int rs = s[threadIdx.x] - v + block_sums[blockIdx.x];
        row_start[i] = rs;
        cursor[i] = rs;
    }
    if (blockIdx.x == 0 && threadIdx.x == 0) row_start[n] = n_edges;
}

// Pass 3: fill csr; XCD p reads bucket p, writes its csr window + cursors —
// all within its 4MB L2.
__global__ __launch_bounds__(256) void fill_bucket_kernel(
    const int2* __restrict__ buckets, const int* __restrict__ bcnt,
    int* __restrict__ cursor, int* __restrict__ csr_src, int cap)
{
    int p = blockIdx.x & (NPART - 1);
    int chunk = blockIdx.x >> 3;
    int n = bcnt[p];
    int i0 = chunk * 1024 + threadIdx.x * 4;
    if (i0 >= n) return;
    const int2* bp = buckets + (size_t)p * cap;
#pragma unroll
    for (int j = 0; j < 4; ++j)
        if (i0 + j < n) {
            int2 e = bp[i0 + j];
            csr_src[atomicAdd(&cursor[e.x], 1)] = e.y;
        }
}

// ---------------- gather aggregation (bf16 neighbors, fp32 self/acc) -------

__device__ __forceinline__ void add_row8(float acc[8], uint4 r) {
    union { unsigned u; float f; } c;
    c.u = r.x << 16;         acc[0] += c.f;
    c.u = r.x & 0xffff0000u; acc[1] += c.f;
    c.u = r.y << 16;         acc[2] += c.f;
    c.u = r.y & 0xffff0000u; acc[3] += c.f;
    c.u = r.z << 16;         acc[4] += c.f;
    c.u = r.z & 0xffff0000u; acc[5] += c.f;
    c.u = r.w << 16;         acc[6] += c.f;
    c.u = r.w & 0xffff0000u; acc[7] += c.f;
}

__global__ __launch_bounds__(256) void gather_agg_bf16_kernel(
    const float* __restrict__ xf,    // fp32 rows (self term)
    const uint4* __restrict__ xb,    // bf16 rows, 16 uint4/row
    const int* __restrict__ row_start, const int* __restrict__ csr_src,
    float* __restrict__ out, int n_nodes)
{
    int t = blockIdx.x * 256 + threadIdx.x;
    int node = t >> 4;
    int lane = t & 15;
    if (node >= n_nodes) return;
    int lo = row_start[node];
    int hi = row_start[node + 1];

    const f32x4* xfr = (const f32x4*)(xf + (size_t)node * IN_DIM + lane * 8);
    f32x4 a0 = __builtin_nontemporal_load(xfr);
    f32x4 a1 = __builtin_nontemporal_load(xfr + 1);
    float acc[8] = {a0.x, a0.y, a0.z, a0.w, a1.x, a1.y, a1.z, a1.w};

    int e = lo;
    for (; e + 3 < hi; e += 4) {
        int s0 = csr_src[e];
        int s1 = csr_src[e + 1];
        int s2 = csr_src[e + 2];
        int s3 = csr_src[e + 3];
        uint4 r0 = xb[(size_t)s0 * 16 + lane];
        uint4 r1 = xb[(size_t)s1 * 16 + lane];
        uint4 r2 = xb[(size_t)s2 * 16 + lane];
        uint4 r3 = xb[(size_t)s3 * 16 + lane];
        add_row8(acc, r0);
        add_row8(acc, r1);
        add_row8(acc, r2);
        add_row8(acc, r3);
    }
    for (; e < hi; ++e) {
        uint4 r = xb[(size_t)csr_src[e] * 16 + lane];
        add_row8(acc, r);
    }

    f32x4 o0 = {acc[0], acc[1], acc[2], acc[3]};
    f32x4 o1 = {acc[4], acc[5], acc[6], acc[7]};
    f32x4* op = (f32x4*)(out + (size_t)node * IN_DIM + lane * 8);
    __builtin_nontemporal_store(o0, op);
    __builtin_nontemporal_store(o1, op + 1);
}

// ---------------- fused MLP: relu(relu(A@Wa+ba)@Wb+bb) ---------------------
// Block = 128 thr (2 waves), 64 rows/block; each wave owns 32 rows (two
// 16-row tiles) sharing W fragments -> 6 MFMAs per 2 W loads, 16 indep acc
// chains. h round-trips LDS (C-layout -> A-frag layout). LDS 33.8KB.
#define HSTRIDE 132

template <bool EMIT_BF16>
__global__ __launch_bounds__(128) void fused_mlp_kernel(
    const float* __restrict__ A,
    const unsigned short* __restrict__ Wa_h, const unsigned short* __restrict__ Wa_l,
    const float* __restrict__ ba,
    const unsigned short* __restrict__ Wb_h, const unsigned short* __restrict__ Wb_l,
    const float* __restrict__ bb,
    float* __restrict__ C, unsigned short* __restrict__ Cb, int M)
{
    __shared__ __align__(16) unsigned short Hh[64][HSTRIDE];
    __shared__ __align__(16) unsigned short Hl[64][HSTRIDE];

    const int t    = threadIdx.x;
    const int wave = t >> 6;                 // 0..1
    const int lane = t & 63;
    const int l15  = lane & 15;
    const int quad = lane >> 4;
    const int wrow0 = wave * 32;             // wave's row base within block
    const int row0  = blockIdx.x * 64 + wrow0;

    f32x4 acc[2][8];
#pragma unroll
    for (int ti = 0; ti < 2; ++ti)
#pragma unroll
        for (int ct = 0; ct < 8; ++ct) acc[ti][ct] = {0.f, 0.f, 0.f, 0.f};

    // ---- stage 1: A (global fp32, split bf16) @ Wa ----
    {
        int ar0 = row0 + l15;
        int ar1 = row0 + 16 + l15;
        const float* ap0 = A + (size_t)((ar0 < M) ? ar0 : (M - 1)) * IN_DIM + quad * 8;
        const float* ap1 = A + (size_t)((ar1 < M) ? ar1 : (M - 1)) * IN_DIM + quad * 8;
#pragma unroll
        for (int k0 = 0; k0 < IN_DIM; k0 += 32) {
            bf16x8 ah[2], al[2];
#pragma unroll
            for (int ti = 0; ti < 2; ++ti) {
                const float* ap = ti ? ap1 : ap0;
                f32x4 v0 = *(const f32x4*)(ap + k0);
                f32x4 v1 = *(const f32x4*)(ap + k0 + 4);
                float v[8] = {v0.x, v0.y, v0.z, v0.w, v1.x, v1.y, v1.z, v1.w};
                unsigned short h[8], l[8];
#pragma unroll
                for (int j = 0; j < 8; ++j) {
                    unsigned short hh = bf16_rne(v[j]);
                    h[j] = hh;
                    l[j] = bf16_rne(v[j] - __uint_as_float(((unsigned)hh) << 16));
                }
                ah[ti] = *(const bf16x8*)h;
                al[ti] = *(const bf16x8*)l;
            }
#pragma unroll
            for (int ct = 0; ct < 8; ++ct) {
                const size_t woff = (size_t)(ct * 16 + l15) * IN_DIM + k0 + quad * 8;
                bf16x8 wh = *(const bf16x8*)(Wa_h + woff);
                bf16x8 wl = *(const bf16x8*)(Wa_l + woff);
                acc[0][ct] = __builtin_amdgcn_mfma_f32_16x16x32_bf16(ah[0], wh, acc[0][ct], 0, 0, 0);
                acc[1][ct] = __builtin_amdgcn_mfma_f32_16x16x32_bf16(ah[1], wh, acc[1][ct], 0, 0, 0);
                acc[0][ct] = __builtin_amdgcn_mfma_f32_16x16x32_bf16(al[0], wh, acc[0][ct], 0, 0, 0);
                acc[1][ct] = __builtin_amdgcn_mfma_f32_16x16x32_bf16(al[1], wh, acc[1][ct], 0, 0, 0);
                acc[0][ct] = __builtin_amdgcn_mfma_f32_16x16x32_bf16(ah[0], wl, acc[0][ct], 0, 0, 0);
                acc[1][ct] = __builtin_amdgcn_mfma_f32_16x16x32_bf16(ah[1], wl, acc[1][ct], 0, 0, 0);
            }
        }
    }

    // ---- epilogue 1: h = relu(acc + ba) -> LDS (split bf16) ----
#pragma unroll
    for (int ti = 0; ti < 2; ++ti) {
#pragma unroll
        for (int ct = 0; ct < 8; ++ct) {
            int col = ct * 16 + l15;
            float b = ba[col];
#pragma unroll
            for (int r = 0; r < 4; ++r) {
                int rl = wrow0 + ti * 16 + quad * 4 + r;
                float v = fmaxf(acc[ti][ct][r] + b, 0.f);
                unsigned short hh = bf16_rne(v);
                Hh[rl][col] = hh;
                Hl[rl][col] = bf16_rne(v - __uint_as_float(((unsigned)hh) << 16));
            }
            acc[ti][ct] = {0.f, 0.f, 0.f, 0.f};
        }
    }
    __syncthreads();

    // ---- stage 2: h (LDS, split bf16) @ Wb ----
#pragma unroll
    for (int k0 = 0; k0 < IN_DIM; k0 += 32) {
        const int hk = k0 + quad * 8;
        bf16x8 ah[2], al[2];
#pragma unroll
        for (int ti = 0; ti < 2; ++ti) {
            const int hr = wrow0 + ti * 16 + l15;
            bf16x4 h0 = *(const bf16x4*)&Hh[hr][hk];
            bf16x4 h1 = *(const bf16x4*)&Hh[hr][hk + 4];
            bf16x4 l0 = *(const bf16x4*)&Hl[hr][hk];
            bf16x4 l1 = *(const bf16x4*)&Hl[hr][hk + 4];
            ah[ti] = __builtin_shufflevector(h0, h1, 0, 1, 2, 3, 4, 5, 6, 7);
            al[ti] = __builtin_shufflevector(l0, l1, 0, 1, 2, 3, 4, 5, 6, 7);
        }
#pragma unroll
        for (int ct = 0; ct < 8; ++ct) {
            const size_t woff = (size_t)(ct * 16 + l15) * IN_DIM + k0 + quad * 8;
            bf16x8 wh = *(const bf16x8*)(Wb_h + woff);
            bf16x8 wl = *(const bf16x8*)(Wb_l + woff);
            acc[0][ct] = __builtin_amdgcn_mfma_f32_16x16x32_bf16(ah[0], wh, acc[0][ct], 0, 0, 0);
            acc[1][ct] = __builtin_amdgcn_mfma_f32_16x16x32_bf16(ah[1], wh, acc[1][ct], 0, 0, 0);
            acc[0][ct] = __builtin_amdgcn_mfma_f32_16x16x32_bf16(al[0], wh, acc[0][ct], 0, 0, 0);
            acc[1][ct] = __builtin_amdgcn_mfma_f32_16x16x32_bf16(al[1], wh, acc[1][ct], 0, 0, 0);
            acc[0][ct] = __builtin_amdgcn_mfma_f32_16x16x32_bf16(ah[0], wl, acc[0][ct], 0, 0, 0);
            acc[1][ct] = __builtin_amdgcn_mfma_f32_16x16x32_bf16(ah[1], wl, acc[1][ct], 0, 0, 0);
        }
    }

    // ---- epilogue 2: out = relu(acc + bb) -> C (+ bf16 mirror) ----
#pragma unroll
    for (int ti = 0; ti < 2; ++ti) {
        const int rbase = row0 + ti * 16 + quad * 4;
#pragma unroll
        for (int ct = 0; ct < 8; ++ct) {
            int col = ct * 16 + l15;
            float b = bb[col];
#pragma unroll
            for (int r = 0; r < 4; ++r) {
                int row = rbase + r;
                if (row < M) {
                    float o = fmaxf(acc[ti][ct][r] + b, 0.f);
                    C[(size_t)row * IN_DIM + col] = o;
                    if (EMIT_BF16)
                        Cb[(size_t)row * IN_DIM + col] = bf16_rne(o);
                }
            }
        }
    }
}

// ---------------- pool + heads ---------------------------------------------

__device__ __forceinline__ int lower_bound_i(const int* __restrict__ a, int n, int v) {
    int lo = 0, hi = n;
    while (lo < hi) {
        int mid = (lo + hi) >> 1;
        if (a[mid] < v) lo = mid + 1; else hi = mid;
    }
    return lo;
}

__global__ __launch_bounds__(128) void pool_kernel(
    const float* __restrict__ h, const int* __restrict__ batch,
    float* __restrict__ pooled, int n_nodes, int n_graphs)
{
    int g = blockIdx.x;
    int lo = lower_bound_i(batch, n_nodes, g);
    int hi = lower_bound_i(batch, n_nodes, g + 1);
    int j = threadIdx.x;
    float acc = 0.f;
    for (int i = lo; i < hi; ++i)
        acc += h[(size_t)i * IN_DIM + j];
    float cnt = (float)(hi - lo);
    pooled[(size_t)g * IN_DIM + j] = acc / fmaxf(cnt, 1.0f);
}

__global__ __launch_bounds__(64) void head_kernel(
    const float* __restrict__ pooled,
    const float* __restrict__ Ws,  const float* __restrict__ bs,
    const float* __restrict__ WlS, const float* __restrict__ blS,
    const float* __restrict__ WlP, const float* __restrict__ blP,
    const float* __restrict__ WnR, const float* __restrict__ bnR,
    float* __restrict__ out, int n_graphs)
{
    int g = blockIdx.x;
    int j = threadIdx.x;
    const float* p = pooled + (size_t)g * IN_DIM;
    float acc = bs[j];
#pragma unroll 8
    for (int k = 0; k < IN_DIM; ++k)
        acc = fmaf(p[k], Ws[k * 64 + j], acc);
    float gj = fmaxf(acc, 0.f);
    float s1 = gj * WlS[j];
    float s2 = gj * WlP[j];
    float s3 = gj * WnR[j];
#pragma unroll
    for (int off = 32; off > 0; off >>= 1) {
        s1 += __shfl_down(s1, off);
        s2 += __shfl_down(s2, off);
        s3 += __shfl_down(s3, off);
    }
    if (j == 0) {
        out[g]                = s1 + blS[0];
        out[n_graphs + g]     = s2 + blP[0];
        out[2 * n_graphs + g] = s3 + bnR[0];
    }
}

// ---------------- launch ---------------------------------------------------

extern "C" void kernel_launch(void* const* d_in, const int* in_sizes, int n_in,
                              void* d_out, int out_size, void* d_ws, size_t ws_size,
                              hipStream_t stream)
{
    const float* x   = (const float*)d_in[0];
    const int*   ei  = (const int*)d_in[1];
    const int*   bat = (const int*)d_in[2];
    const float* W1a = (const float*)d_in[3];
    const float* b1a = (const float*)d_in[4];
    const float* W1b = (const float*)d_in[5];
    const float* b1b = (const float*)d_in[6];
    const float* W2a = (const float*)d_in[7];
    const float* b2a = (const float*)d_in[8];
    const float* W2b = (const float*)d_in[9];
    const float* b2b = (const float*)d_in[10];
    const float* Ws  = (const float*)d_in[11];
    const float* bs  = (const float*)d_in[12];
    const float* WlS = (const float*)d_in[13];
    const float* blS = (const float*)d_in[14];
    const float* WlP = (const float*)d_in[15];
    const float* blP = (const float*)d_in[16];
    const float* WnR = (const float*)d_in[17];
    const float* bnR = (const float*)d_in[18];

    const int n_nodes  = in_sizes[0] / IN_DIM;
    const int n_edges  = in_sizes[1] / 2;
    const int n_graphs = out_size / 3;
    const int* src = ei;
    const int* dst = ei + n_edges;

    const size_t node_elems   = (size_t)n_nodes * IN_DIM;
    const size_t pooled_elems = (size_t)n_graphs * IN_DIM;

    float* xbf    = (float*)d_ws;               // bf16 mirror slot
    float* buf2   = xbf  + node_elems;
    float* bufA   = buf2 + node_elems;          // gather output; buckets alias
    float* pooled = bufA + node_elems;
    int* row_start = (int*)(pooled + pooled_elems);   // n_nodes + 1
    int* cursor    = row_start + (n_nodes + 1);       // n_nodes
    int* bcur      = cursor + n_nodes;                // 8 bucket cursors/counts
    int* csr_src   = bcur + NPART;                    // n_edges
    unsigned short* wt_h = (unsigned short*)(csr_src + n_edges);  // 4 * 16384
    unsigned short* wt_l = wt_h + 4 * 16384;

    unsigned short* xb = (unsigned short*)xbf;
    const int cap = n_edges / NPART + 65536;          // bucket capacity (>150 sigma)
    int2* buckets = (int2*)bufA;                      // 8*cap*8B = 17MB <= 25.6MB

    const int nblocks256 = (n_nodes + 255) / 256;
    const int gatherblocks = (int)(((size_t)n_nodes * 16 + 255) / 256);
    const int mlpblocks = (n_nodes + 63) / 64;
    const int binblocks = (n_edges + 1023) / 1024;
    const int bucketblocks = NPART * ((cap + 1023) / 1024);
    const int n8 = (int)(node_elems / 8);
    const int cvtblocks = (n8 + 255) / 256;

    // ---- weight conversion + CSR build ----
    conv_weights_kernel<<<256, 256, 0, stream>>>(W1a, W1b, W2a, W2b, wt_h, wt_l);
    hipMemsetAsync(cursor, 0, (size_t)(n_nodes + NPART) * sizeof(int), stream);
    bin_kernel<<<binblocks, 256, 0, stream>>>(src, dst, buckets, bcur,
                                              n_edges, n_nodes, cap);
    hist_bucket_kernel<<<bucketblocks, 256, 0, stream>>>(buckets, bcur, cursor, cap);
    scan_phaseA<<<nblocks256, 256, 0, stream>>>(cursor, csr_src /*scratch*/, n_nodes);
    scan_phaseB<<<1, 256, 0, stream>>>(csr_src, nblocks256);
    scan_phaseC<<<nblocks256, 256, 0, stream>>>(cursor, csr_src, row_start,
                                                cursor, n_nodes, n_edges);
    fill_bucket_kernel<<<bucketblocks, 256, 0, stream>>>(buckets, bcur, cursor,
                                                         csr_src, cap);

    // ---- layer 1 ----
    f32_to_bf16_kernel<<<cvtblocks, 256, 0, stream>>>((const float4*)x, (uint4*)xb, n8);
    gather_agg_bf16_kernel<<<gatherblocks, 256, 0, stream>>>(
        x, (const uint4*)xb, row_start, csr_src, bufA, n_nodes);
    fused_mlp_kernel<true><<<mlpblocks, 128, 0, stream>>>(
        bufA, wt_h, wt_l, b1a, wt_h + 16384, wt_l + 16384, b1b,
        buf2, xb, n_nodes);

    // ---- layer 2 ----
    gather_agg_bf16_kernel<<<gatherblocks, 256, 0, stream>>>(
        buf2, (const uint4*)xb, row_start, csr_src, bufA, n_nodes);
    fused_mlp_kernel<false><<<mlpblocks, 128, 0, stream>>>(
        bufA, wt_h + 2 * 16384, wt_l + 2 * 16384, b2a,
        wt_h + 3 * 16384, wt_l + 3 * 16384, b2b,
        buf2, nullptr, n_nodes);

    // ---- pool + heads ----
    pool_kernel<<<n_graphs, 128, 0, stream>>>(buf2, bat, pooled, n_nodes, n_graphs);
    head_kernel<<<n_graphs, 64, 0, stream>>>(pooled, Ws, bs, WlS, blS, WlP, blP,
                                             WnR, bnR, (float*)d_out, n_graphs);
}